// Round 15
// baseline (107.619 us; speedup 1.0000x reference)
//
#include <hip/hip_runtime.h>
#include <hip/hip_bf16.h>
#include <math.h>

#define KK 5
#define Bc 5.0f
#define NN 32768
#define DD 64
#define LL 63
#define PP 14
#define MIN_Wc 0.001f
#define MIN_Hc 0.001f
#define MIN_Dc 0.001f
#define LOG2E 1.44269504088896340736f
#define TWOLOG2E 2.88539008177792681472f
#define LN2 0.69314718055994530942f

typedef float f4 __attribute__((ext_vector_type(4)));
typedef float f32x4 __attribute__((ext_vector_type(4)));
typedef float f2 __attribute__((ext_vector_type(2)));
typedef short short8 __attribute__((ext_vector_type(8)));

__device__ __forceinline__ float rcp_fast(float v)   { return __builtin_amdgcn_rcpf(v); }
__device__ __forceinline__ float exp2_fast(float v)  { return __builtin_amdgcn_exp2f(v); }  // v_exp_f32: 2^x
__device__ __forceinline__ float log2_fast(float v)  { return __builtin_amdgcn_logf(v); }   // v_log_f32: log2
// input pre-scaled by 2*log2(e): tanh(x) = 1 - 2/(2^(2x*log2e)+1)
__device__ __forceinline__ float tanh_pre(float t2) {
    float e = exp2_fast(t2);
    return 1.0f - 2.0f * rcp_fast(e + 1.0f);
}
// input pre-scaled by log2(e): softplus(v) = ln2*log2(1+2^(v*log2e))
__device__ __forceinline__ float softplus2(float v2) {
    return (v2 > 21.7f) ? LN2 * v2 : LN2 * log2_fast(1.0f + exp2_fast(v2));
}
__device__ __forceinline__ ushort to_bf16u(float v) {
    __hip_bfloat16 b = __float2bfloat16(v);
    return *(ushort*)&b;
}
__device__ __forceinline__ float bflo(unsigned u) { return __uint_as_float(u << 16); }
__device__ __forceinline__ float bfhi(unsigned u) { return __uint_as_float(u & 0xFFFF0000u); }
__device__ __forceinline__ f2 splat2(float v) { f2 r; r.x = v; r.y = v; return r; }
__device__ __forceinline__ f4 splat4(float v) { f4 r; r.x = v; r.y = v; r.z = v; r.w = v; return r; }

// ---------------- kernel 0: pack W1 fp32 -> bf16 B[512][64] (n-major) -------
__global__ __launch_bounds__(256) void pack_b1(const float* __restrict__ W1,
                                               ushort* __restrict__ Bp) {
    int id = blockIdx.x * 256 + threadIdx.x;     // 0..32767
    int n = id >> 6, k = id & 63;
    float v = 0.f;
    if (n < 504 && k < 63) {
        int l = n >> 3, h = n & 7;
        v = W1[(l * 63 + k) * 8 + h];
    }
    Bp[id] = to_bf16u(v);
}

__device__ __forceinline__ short8 pack_a(f4 v0, f4 v1) {
    short8 a;
    a[0] = (short)to_bf16u(v0.x); a[1] = (short)to_bf16u(v0.y);
    a[2] = (short)to_bf16u(v0.z); a[3] = (short)to_bf16u(v0.w);
    a[4] = (short)to_bf16u(v1.x); a[5] = (short)to_bf16u(v1.y);
    a[6] = (short)to_bf16u(v1.z); a[7] = (short)to_bf16u(v1.w);
    return a;
}

// per-dim LDS weight slot (floats, stride 216 = 864B, 16B-aligned):
// [0,64) 2log2e*W2[h][g]  [64,72) 2log2e*b2  [72,200) log2e*W3 padded [g][16]  [200,216) log2e*b3
#define WSL 216
#define H1S 72    // u16 row stride: 144B = 36 words == 4 mod 32 (proven residue)

// ---- one dim, TWO samples per lane; NO local arrays (SROA-safe) ------------
__device__ __forceinline__ void do_dim2(
    int dd, const float* wp, float xf0, float xf1, uint4 hv0, uint4 hv1,
    int s0, int lane, int bx,
    const float* __restrict__ ip, float* __restrict__ out)
{
    // h1 unpack to scalars
    float h0_0 = bflo(hv0.x), h1_0 = bflo(hv1.x);
    float h0_1 = bfhi(hv0.x), h1_1 = bfhi(hv1.x);
    float h0_2 = bflo(hv0.y), h1_2 = bflo(hv1.y);
    float h0_3 = bfhi(hv0.y), h1_3 = bfhi(hv1.y);
    float h0_4 = bflo(hv0.z), h1_4 = bflo(hv1.z);
    float h0_5 = bfhi(hv0.z), h1_5 = bfhi(hv1.z);
    float h0_6 = bflo(hv0.w), h1_6 = bflo(hv1.w);
    float h0_7 = bfhi(hv0.w), h1_7 = bfhi(hv1.w);

    // layer 2: weights loaded once, two sample chains (weights pre-scaled 2log2e)
    f4 a0 = *(const f4*)(wp + 64), b0 = *(const f4*)(wp + 68);
    f4 a1 = a0, b1 = b0;
#define L2STEP(HI, X0, X1) { \
    f4 wa = *(const f4*)(wp + (HI) * 8); \
    f4 wb = *(const f4*)(wp + (HI) * 8 + 4); \
    f4 v0 = splat4(X0), v1 = splat4(X1); \
    a0 += v0 * wa; a1 += v1 * wa; \
    b0 += v0 * wb; b1 += v1 * wb; }
    L2STEP(0, h0_0, h1_0)
    L2STEP(1, h0_1, h1_1)
    L2STEP(2, h0_2, h1_2)
    L2STEP(3, h0_3, h1_3)
    L2STEP(4, h0_4, h1_4)
    L2STEP(5, h0_5, h1_5)
    L2STEP(6, h0_6, h1_6)
    L2STEP(7, h0_7, h1_7)
#undef L2STEP
    float g0_0 = tanh_pre(a0.x), g1_0 = tanh_pre(a1.x);
    float g0_1 = tanh_pre(a0.y), g1_1 = tanh_pre(a1.y);
    float g0_2 = tanh_pre(a0.z), g1_2 = tanh_pre(a1.z);
    float g0_3 = tanh_pre(a0.w), g1_3 = tanh_pre(a1.w);
    float g0_4 = tanh_pre(b0.x), g1_4 = tanh_pre(b1.x);
    float g0_5 = tanh_pre(b0.y), g1_5 = tanh_pre(b1.y);
    float g0_6 = tanh_pre(b0.z), g1_6 = tanh_pre(b1.z);
    float g0_7 = tanh_pre(b0.w), g1_7 = tanh_pre(b1.w);

    // layer 3: shared weights (pre-scaled log2e), two chains x 4 accumulators
    f4 pa0 = *(const f4*)(wp + 200), pb0 = *(const f4*)(wp + 204);
    f4 pc0 = *(const f4*)(wp + 208), pd0 = *(const f4*)(wp + 212);
    f4 pa1 = pa0, pb1 = pb0, pc1 = pc0, pd1 = pd0;
#define L3STEP(GI, X0, X1) { \
    const float* wr = wp + 72 + (GI) * 16; \
    f4 w0 = *(const f4*)(wr); \
    f4 w1 = *(const f4*)(wr + 4); \
    f4 w2 = *(const f4*)(wr + 8); \
    f4 w3 = *(const f4*)(wr + 12); \
    f4 v0 = splat4(X0), v1 = splat4(X1); \
    pa0 += v0 * w0; pa1 += v1 * w0; \
    pb0 += v0 * w1; pb1 += v1 * w1; \
    pc0 += v0 * w2; pc1 += v1 * w2; \
    pd0 += v0 * w3; pd1 += v1 * w3; }
    L3STEP(0, g0_0, g1_0)
    L3STEP(1, g0_1, g1_1)
    L3STEP(2, g0_2, g1_2)
    L3STEP(3, g0_3, g1_3)
    L3STEP(4, g0_4, g1_4)
    L3STEP(5, g0_5, g1_5)
    L3STEP(6, g0_6, g1_6)
    L3STEP(7, g0_7, g1_7)
#undef L3STEP

    // p scalars, already in log2 domain (no arrays!)
    float p0_0 = pa0.x, p0_1 = pa0.y, p0_2 = pa0.z, p0_3 = pa0.w;
    float p0_4 = pb0.x, p0_5 = pb0.y, p0_6 = pb0.z, p0_7 = pb0.w;
    float p0_8 = pc0.x, p0_9 = pc0.y, p0_10 = pc0.z, p0_11 = pc0.w;
    float p0_12 = pd0.x, p0_13 = pd0.y;
    float p1_0 = pa1.x, p1_1 = pa1.y, p1_2 = pa1.z, p1_3 = pa1.w;
    float p1_4 = pb1.x, p1_5 = pb1.y, p1_6 = pb1.z, p1_7 = pb1.w;
    float p1_8 = pc1.x, p1_9 = pc1.y, p1_10 = pc1.z, p1_11 = pc1.w;
    float p1_12 = pd1.x, p1_13 = pd1.y;

    if (dd == 0) {   // wave-uniform override; convert to log2 domain
        p0_0 = LOG2E * ip[0];  p0_1 = LOG2E * ip[1];  p0_2 = LOG2E * ip[2];
        p0_3 = LOG2E * ip[3];  p0_4 = LOG2E * ip[4];  p0_5 = LOG2E * ip[5];
        p0_6 = LOG2E * ip[6];  p0_7 = LOG2E * ip[7];  p0_8 = LOG2E * ip[8];
        p0_9 = LOG2E * ip[9];  p0_10 = LOG2E * ip[10]; p0_11 = LOG2E * ip[11];
        p0_12 = LOG2E * ip[12]; p0_13 = LOG2E * ip[13];
        p1_0 = p0_0;  p1_1 = p0_1;  p1_2 = p0_2;  p1_3 = p0_3;
        p1_4 = p0_4;  p1_5 = p0_5;  p1_6 = p0_6;  p1_7 = p0_7;
        p1_8 = p0_8;  p1_9 = p0_9;  p1_10 = p0_10; p1_11 = p0_11;
        p1_12 = p0_12; p1_13 = p0_13;
    }

    // ---- packed spline: f4 lanes = (w_s0, h_s0, w_s1, h_s1); raw v_exp ----
    f4 e0, e1, e2, e3, e4;
    e0.x = exp2_fast(p0_0); e0.y = exp2_fast(p0_5); e0.z = exp2_fast(p1_0); e0.w = exp2_fast(p1_5);
    e1.x = exp2_fast(p0_1); e1.y = exp2_fast(p0_6); e1.z = exp2_fast(p1_1); e1.w = exp2_fast(p1_6);
    e2.x = exp2_fast(p0_2); e2.y = exp2_fast(p0_7); e2.z = exp2_fast(p1_2); e2.w = exp2_fast(p1_7);
    e3.x = exp2_fast(p0_3); e3.y = exp2_fast(p0_8); e3.z = exp2_fast(p1_3); e3.w = exp2_fast(p1_8);
    e4.x = exp2_fast(p0_4); e4.y = exp2_fast(p0_9); e4.z = exp2_fast(p1_4); e4.w = exp2_fast(p1_9);
    f4 es = (e0 + e1) + (e2 + e3) + e4;
    f4 nrm;
    nrm.x = 0.995f * rcp_fast(es.x); nrm.y = 0.995f * rcp_fast(es.y);
    nrm.z = 0.995f * rcp_fast(es.z); nrm.w = 0.995f * rcp_fast(es.w);

    const f4 minv = {MIN_Wc, MIN_Hc, MIN_Wc, MIN_Hc};
    f4 acc4 = splat4(0.f);
    acc4 += minv + nrm * e0;  f4 cb1 = splat4(2.f * Bc) * acc4 - splat4(Bc);
    acc4 += minv + nrm * e1;  f4 cb2 = splat4(2.f * Bc) * acc4 - splat4(Bc);
    acc4 += minv + nrm * e2;  f4 cb3 = splat4(2.f * Bc) * acc4 - splat4(Bc);
    acc4 += minv + nrm * e3;  f4 cb4 = splat4(2.f * Bc) * acc4 - splat4(Bc);

    const float xc0 = fminf(fmaxf(xf0, -Bc), Bc);
    const float xc1 = fminf(fmaxf(xf1, -Bc), Bc);

    // bin select: track LOWER and UPPER boundaries; widths via one sub at end
    float icw0 = -Bc, ich0 = -Bc, hw0 = cb1.x, hh0 = cb1.y;
    float icw1 = -Bc, ich1 = -Bc, hw1 = cb1.z, hh1 = cb1.w;
    float rv0 = p0_10, rvp0 = p0_10, rv1 = p1_10, rvp1 = p1_10;
    bool vone0 = true, vpone0 = false, vone1 = true, vpone1 = false;
    {
        bool c0 = xc0 >= cb1.x;               bool c1 = xc1 >= cb1.z;
        icw0 = c0 ? cb1.x : icw0;             icw1 = c1 ? cb1.z : icw1;
        ich0 = c0 ? cb1.y : ich0;             ich1 = c1 ? cb1.w : ich1;
        hw0  = c0 ? cb2.x : hw0;              hw1  = c1 ? cb2.z : hw1;
        hh0  = c0 ? cb2.y : hh0;              hh1  = c1 ? cb2.w : hh1;
        vone0 = c0 ? false : vone0;           vone1 = c1 ? false : vone1;
        rv0  = c0 ? p0_10 : rv0;              rv1  = c1 ? p1_10 : rv1;
        rvp0 = c0 ? p0_11 : rvp0;             rvp1 = c1 ? p1_11 : rvp1;
    }
    {
        bool c0 = xc0 >= cb2.x;               bool c1 = xc1 >= cb2.z;
        icw0 = c0 ? cb2.x : icw0;             icw1 = c1 ? cb2.z : icw1;
        ich0 = c0 ? cb2.y : ich0;             ich1 = c1 ? cb2.w : ich1;
        hw0  = c0 ? cb3.x : hw0;              hw1  = c1 ? cb3.z : hw1;
        hh0  = c0 ? cb3.y : hh0;              hh1  = c1 ? cb3.w : hh1;
        rv0  = c0 ? p0_11 : rv0;              rv1  = c1 ? p1_11 : rv1;
        rvp0 = c0 ? p0_12 : rvp0;             rvp1 = c1 ? p1_12 : rvp1;
    }
    {
        bool c0 = xc0 >= cb3.x;               bool c1 = xc1 >= cb3.z;
        icw0 = c0 ? cb3.x : icw0;             icw1 = c1 ? cb3.z : icw1;
        ich0 = c0 ? cb3.y : ich0;             ich1 = c1 ? cb3.w : ich1;
        hw0  = c0 ? cb4.x : hw0;              hw1  = c1 ? cb4.z : hw1;
        hh0  = c0 ? cb4.y : hh0;              hh1  = c1 ? cb4.w : hh1;
        rv0  = c0 ? p0_12 : rv0;              rv1  = c1 ? p1_12 : rv1;
        rvp0 = c0 ? p0_13 : rvp0;             rvp1 = c1 ? p1_13 : rvp1;
    }
    {
        bool c0 = xc0 >= cb4.x;               bool c1 = xc1 >= cb4.z;
        icw0 = c0 ? cb4.x : icw0;             icw1 = c1 ? cb4.z : icw1;
        ich0 = c0 ? cb4.y : ich0;             ich1 = c1 ? cb4.w : ich1;
        hw0  = c0 ? Bc : hw0;                 hw1  = c1 ? Bc : hw1;
        hh0  = c0 ? Bc : hh0;                 hh1  = c1 ? Bc : hh1;
        rv0  = c0 ? p0_13 : rv0;              rv1  = c1 ? p1_13 : rv1;
        vpone0 = c0;                          vpone1 = c1;
    }
    const float ibw0 = hw0 - icw0, ih0 = hh0 - ich0;
    const float ibw1 = hw1 - icw1, ih1 = hh1 - ich1;
    const float idv0   = vone0  ? 1.0f : MIN_Dc + softplus2(rv0);
    const float idv1   = vone1  ? 1.0f : MIN_Dc + softplus2(rv1);
    const float idvp0  = vpone0 ? 1.0f : MIN_Dc + softplus2(rvp0);
    const float idvp1_ = vpone1 ? 1.0f : MIN_Dc + softplus2(rvp1);

    const float ibr0 = rcp_fast(ibw0);        const float ibr1 = rcp_fast(ibw1);
    const float idl0 = ih0 * ibr0;            const float idl1 = ih1 * ibr1;
    const float th0 = (xc0 - icw0) * ibr0;    const float th1 = (xc1 - icw1) * ibr1;
    const float om0 = 1.0f - th0;             const float om1 = 1.0f - th1;
    const float tm0 = th0 * om0;              const float tm1 = th1 * om1;
    const float num0 = ih0 * (idl0 * th0 * th0 + idv0 * tm0);
    const float num1 = ih1 * (idl1 * th1 * th1 + idv1 * tm1);
    const float den0 = idl0 + (idv0 + idvp0 - 2.0f * idl0) * tm0;
    const float den1 = idl1 + (idv1 + idvp1_ - 2.0f * idl1) * tm1;
    const float dr0 = rcp_fast(den0);         const float dr1 = rcp_fast(den1);
    const float out0 = ich0 + num0 * dr0;     const float out1v = ich1 + num1 * dr1;
    const float dn0 = idl0 * idl0 * (idvp0 * th0 * th0 + 2.0f * idl0 * tm0 + idv0 * om0 * om0);
    const float dn1 = idl1 * idl1 * (idvp1_ * th1 * th1 + 2.0f * idl1 * tm1 + idv1 * om1 * om1);
    const float ld0 = LN2 * log2_fast(dn0 * dr0 * dr0);
    const float ld1 = LN2 * log2_fast(dn1 * dr1 * dr1);

    const bool in0 = (xf0 >= -Bc) && (xf0 <= Bc);
    const bool in1 = (xf1 >= -Bc) && (xf1 <= Bc);
    const float z0 = in0 ? out0 : xf0;        const float z1 = in1 ? out1v : xf1;
    float lv0 = in0 ? ld0 : 0.0f;             float lv1 = in1 ? ld1 : 0.0f;

    out[dd * NN + s0 + lane] = z0;            // coalesced
    out[dd * NN + s0 + 64 + lane] = z1;

    #pragma unroll
    for (int off = 32; off > 0; off >>= 1) {
        lv0 += __shfl_down(lv0, off);
        lv1 += __shfl_down(lv1, off);
    }
    if (lane == 0) {
        out[NN * DD + dd * (NN / 64) + 2 * bx]     = lv0;
        out[NN * DD + dd * (NN / 64) + 2 * bx + 1] = lv1;
    }
}

// ---------------- fused kernel -----------------------------------------------
// grid (256, 8): x = 128-sample tile, y = 8-dim group (y==7 slot7 -> dim 0).
// causality: y<4 -> l<32 -> only k<32 contributes (W1 pre-masked) -> 1 MFMA.
// launch_bounds(256,6): LDS 25.3KB allows 6 blocks/CU -> 24 waves/CU (75%);
// VGPR cap ~85 (R12-family measured 64 -> expected to fit without spill).
__global__ __launch_bounds__(256, 6) void fused_kernel(
    const float* __restrict__ x, const float* __restrict__ init_param,
    const ushort* __restrict__ Bp, const float* __restrict__ b1,
    const float* __restrict__ W2, const float* __restrict__ b2,
    const float* __restrict__ W3, const float* __restrict__ b3,
    float* __restrict__ out)
{
    __shared__ ushort h1c[128 * H1S];    // 18432 B
    __shared__ float  wl[8 * WSL];       // 6912 B  -> total 25344 B
    const int tid = threadIdx.x;
    const int s0 = blockIdx.x * 128;
    const int y  = blockIdx.y;
    const int bx = blockIdx.x;
    const int lane = tid & 63;
    const int wave = __builtin_amdgcn_readfirstlane(tid >> 6);
    const int ln = lane & 15, qg = lane >> 4;
    const int l0 = y * 8;

    // spline x values for this wave's 2 dims x 2 sample-halves
    const int dA = y * 8 + 1 + 2 * wave;
    const int dB = (y == 7 && wave == 3) ? 0 : dA + 1;
    const float* xr0 = x + (size_t)(s0 + lane) * 64;
    const float* xr1 = xr0 + 64 * 64;
    float xA0 = xr0[dA], xA1 = xr1[dA];
    float xB0 = xr0[dB], xB1 = xr1[dB];

    // A-fragments for two m-tiles (rows wave*16 and 64+wave*16)
    short8 a0_0, a1_0, a0_1, a1_1;
    {
        const float* p0 = x + (size_t)(s0 + wave * 16 + ln) * 64 + qg * 8;
        const float* p1 = p0 + 64 * 64;
        a0_0 = pack_a(*(const f4*)p0, *(const f4*)(p0 + 4));
        a0_1 = pack_a(*(const f4*)p1, *(const f4*)(p1 + 4));
        if (y >= 4) {
            a1_0 = pack_a(*(const f4*)(p0 + 32), *(const f4*)(p0 + 36));
            a1_1 = pack_a(*(const f4*)(p1 + 32), *(const f4*)(p1 + 36));
        } else { a1_0 = a0_0; a1_1 = a0_1; }
    }

    // ---- stage this block's 8 dims of weights into LDS (log2-domain scaled) ----
    if (tid < 128) {   // W2: 8 slots x 64 floats, f4, x 2log2e
        int s = tid >> 4, o = (tid & 15) * 4;
        if (l0 + s < LL)
            *(f4*)&wl[s * WSL + o] = splat4(TWOLOG2E) * (*(const f4*)&W2[(l0 + s) * 64 + o]);
    }
    if (tid < 64) {    // b2: 8 x 8, x 2log2e
        int s = tid >> 3, o = tid & 7;
        if (l0 + s < LL) wl[s * WSL + 64 + o] = TWOLOG2E * b2[(l0 + s) * 8 + o];
    }
    #pragma unroll
    for (int q0 = 0; q0 < 448; q0 += 256) {   // W3: 8 slots x 56 f2, x log2e
        int q = q0 + tid;
        if (q < 448) {
            int s = q / 56, r = q % 56, g = r / 7, o = r % 7;
            if (l0 + s < LL)
                *(f2*)&wl[s * WSL + 72 + g * 16 + o * 2] =
                    splat2(LOG2E) * (*(const f2*)&W3[(l0 + s) * 112 + g * 14 + o * 2]);
        }
    }
    if (tid < 64) {    // zero W3 pad cols 14,15
        int s = tid >> 3, g = tid & 7;
        *(f2*)&wl[s * WSL + 72 + g * 16 + 14] = splat2(0.f);
    }
    if (tid < 112) {   // b3: 8 x 14, x log2e
        int s = tid / 14, o = tid % 14;
        wl[s * WSL + 200 + o] = LOG2E * b3[(l0 + s < LL ? l0 + s : 0) * PP + o];
    }
    if (tid < 16) {    // zero b3 pad
        int s = tid >> 1, o = 214 + (tid & 1);
        wl[s * WSL + o] = 0.f;
    }

    // ---- phase 1: MFMA 64 outcols x two 16-row m-tiles ----
    #pragma unroll
    for (int nt = 0; nt < 4; ++nt) {
        int ncol = y * 64 + nt * 16 + ln;
        const short8* bp8 = (const short8*)(Bp + ncol * 64 + qg * 8);
        short8 bf0 = bp8[0];
        f32x4 acc0 = {0.f, 0.f, 0.f, 0.f};
        f32x4 acc1 = {0.f, 0.f, 0.f, 0.f};
        acc0 = __builtin_amdgcn_mfma_f32_16x16x32_bf16(a0_0, bf0, acc0, 0, 0, 0);
        acc1 = __builtin_amdgcn_mfma_f32_16x16x32_bf16(a0_1, bf0, acc1, 0, 0, 0);
        if (y >= 4) {
            short8 bf1 = bp8[4];
            acc0 = __builtin_amdgcn_mfma_f32_16x16x32_bf16(a1_0, bf1, acc0, 0, 0, 0);
            acc1 = __builtin_amdgcn_mfma_f32_16x16x32_bf16(a1_1, bf1, acc1, 0, 0, 0);
        }
        float bias2 = (ncol < 504) ? TWOLOG2E * b1[ncol] : 0.f;
        #pragma unroll
        for (int r = 0; r < 4; ++r) {
            int row = wave * 16 + qg * 4 + r;
            float v0 = tanh_pre(fmaf(TWOLOG2E, acc0[r], bias2));
            float v1 = tanh_pre(fmaf(TWOLOG2E, acc1[r], bias2));
            h1c[row * H1S + nt * 16 + ln] = to_bf16u(v0);
            h1c[(row + 64) * H1S + nt * 16 + ln] = to_bf16u(v1);
        }
    }
    __syncthreads();   // the only barrier (covers weight staging + h1c)

    // h1 fragments: 2 dims x 2 sample-halves
    const int slA = 2 * wave, slB = 2 * wave + 1;
    uint4 hA0 = *(const uint4*)&h1c[lane * H1S + slA * 8];
    uint4 hA1 = *(const uint4*)&h1c[(lane + 64) * H1S + slA * 8];
    uint4 hB0 = *(const uint4*)&h1c[lane * H1S + slB * 8];
    uint4 hB1 = *(const uint4*)&h1c[(lane + 64) * H1S + slB * 8];

    // ---- phase 2: 2 dims, each with 2-sample ILP ----
    do_dim2(dA, wl + slA * WSL, xA0, xA1, hA0, hA1, s0, lane, bx, init_param, out);
    do_dim2(dB, wl + slB * WSL, xB0, xB1, hB0, hB1, s0, lane, bx, init_param, out);
}

extern "C" void kernel_launch(void* const* d_in, const int* in_sizes, int n_in,
                              void* d_out, int out_size, void* d_ws, size_t ws_size,
                              hipStream_t stream) {
    const float* x          = (const float*)d_in[0];
    const float* init_param = (const float*)d_in[1];
    const float* W1         = (const float*)d_in[2];
    const float* b1         = (const float*)d_in[3];
    const float* W2         = (const float*)d_in[4];
    const float* b2         = (const float*)d_in[5];
    const float* W3         = (const float*)d_in[6];
    const float* b3         = (const float*)d_in[7];
    float* out = (float*)d_out;

    ushort* Bp = (ushort*)d_ws;            // 512*64 bf16 = 64 KB

    pack_b1<<<128, 256, 0, stream>>>(W1, Bp);
    fused_kernel<<<dim3(256, 8), 256, 0, stream>>>(x, init_param, Bp, b1,
                                                   W2, b2, W3, b3, out);
}

// Round 16
// 105.000 us; speedup vs baseline: 1.0249x; 1.0249x over previous
//
#include <hip/hip_runtime.h>
#include <hip/hip_bf16.h>
#include <math.h>

#define KK 5
#define Bc 5.0f
#define NN 32768
#define DD 64
#define LL 63
#define PP 14
#define MIN_Wc 0.001f
#define MIN_Hc 0.001f
#define MIN_Dc 0.001f
#define LOG2E 1.44269504088896340736f
#define TWOLOG2E 2.88539008177792681472f
#define LN2 0.69314718055994530942f

typedef float f4 __attribute__((ext_vector_type(4)));
typedef float f32x4 __attribute__((ext_vector_type(4)));
typedef float f2 __attribute__((ext_vector_type(2)));
typedef short short8 __attribute__((ext_vector_type(8)));

__device__ __forceinline__ float rcp_fast(float v)   { return __builtin_amdgcn_rcpf(v); }
__device__ __forceinline__ float exp2_fast(float v)  { return __builtin_amdgcn_exp2f(v); }  // v_exp_f32: 2^x
__device__ __forceinline__ float log2_fast(float v)  { return __builtin_amdgcn_logf(v); }   // v_log_f32: log2
// input pre-scaled by 2*log2(e): tanh(x) = 1 - 2/(2^(2x*log2e)+1)
__device__ __forceinline__ float tanh_pre(float t2) {
    float e = exp2_fast(t2);
    return 1.0f - 2.0f * rcp_fast(e + 1.0f);
}
// input pre-scaled by log2(e): softplus(v) = ln2*log2(1+2^(v*log2e))
__device__ __forceinline__ float softplus2(float v2) {
    return (v2 > 21.7f) ? LN2 * v2 : LN2 * log2_fast(1.0f + exp2_fast(v2));
}
// RNE (for one-time weight pack only)
__device__ __forceinline__ ushort to_bf16u(float v) {
    __hip_bfloat16 b = __float2bfloat16(v);
    return *(ushort*)&b;
}
// truncating bf16 (1 shift) — hot-path; error ≤1ulp bf16, absmax margin is 4x
__device__ __forceinline__ ushort to_bf16t(float v) {
    return (ushort)(__float_as_uint(v) >> 16);
}
__device__ __forceinline__ float bflo(unsigned u) { return __uint_as_float(u << 16); }
__device__ __forceinline__ float bfhi(unsigned u) { return __uint_as_float(u & 0xFFFF0000u); }
__device__ __forceinline__ f2 splat2(float v) { f2 r; r.x = v; r.y = v; return r; }
__device__ __forceinline__ f4 splat4(float v) { f4 r; r.x = v; r.y = v; r.z = v; r.w = v; return r; }

// ---------------- kernel 0: pack W1 fp32 -> bf16 B[512][64] (n-major) -------
__global__ __launch_bounds__(256) void pack_b1(const float* __restrict__ W1,
                                               ushort* __restrict__ Bp) {
    int id = blockIdx.x * 256 + threadIdx.x;     // 0..32767
    int n = id >> 6, k = id & 63;
    float v = 0.f;
    if (n < 504 && k < 63) {
        int l = n >> 3, h = n & 7;
        v = W1[(l * 63 + k) * 8 + h];
    }
    Bp[id] = to_bf16u(v);   // RNE here (one-time)
}

__device__ __forceinline__ short8 pack_a(f4 v0, f4 v1) {
    short8 a;
    a[0] = (short)to_bf16t(v0.x); a[1] = (short)to_bf16t(v0.y);
    a[2] = (short)to_bf16t(v0.z); a[3] = (short)to_bf16t(v0.w);
    a[4] = (short)to_bf16t(v1.x); a[5] = (short)to_bf16t(v1.y);
    a[6] = (short)to_bf16t(v1.z); a[7] = (short)to_bf16t(v1.w);
    return a;
}

// per-dim LDS weight slot (floats, stride 216 = 864B, 16B-aligned):
// [0,64) 2log2e*W2[h][g]  [64,72) 2log2e*b2  [72,200) log2e*W3 padded [g][16]  [200,216) log2e*b3
#define WSL 216
#define H1S 72    // u16 row stride: 144B = 36 words == 4 mod 32 (proven residue)

// ---- one dim, TWO samples per lane; NO local arrays (SROA-safe) ------------
__device__ __forceinline__ void do_dim2(
    int dd, const float* wp, float xf0, float xf1, uint4 hv0, uint4 hv1,
    int s0, int lane, int bx,
    const float* __restrict__ ip, float* __restrict__ out)
{
    // h1 unpack to scalars
    float h0_0 = bflo(hv0.x), h1_0 = bflo(hv1.x);
    float h0_1 = bfhi(hv0.x), h1_1 = bfhi(hv1.x);
    float h0_2 = bflo(hv0.y), h1_2 = bflo(hv1.y);
    float h0_3 = bfhi(hv0.y), h1_3 = bfhi(hv1.y);
    float h0_4 = bflo(hv0.z), h1_4 = bflo(hv1.z);
    float h0_5 = bfhi(hv0.z), h1_5 = bfhi(hv1.z);
    float h0_6 = bflo(hv0.w), h1_6 = bflo(hv1.w);
    float h0_7 = bfhi(hv0.w), h1_7 = bfhi(hv1.w);

    // layer 2: weights loaded once, two sample chains (weights pre-scaled 2log2e)
    f4 a0 = *(const f4*)(wp + 64), b0 = *(const f4*)(wp + 68);
    f4 a1 = a0, b1 = b0;
#define L2STEP(HI, X0, X1) { \
    f4 wa = *(const f4*)(wp + (HI) * 8); \
    f4 wb = *(const f4*)(wp + (HI) * 8 + 4); \
    f4 v0 = splat4(X0), v1 = splat4(X1); \
    a0 += v0 * wa; a1 += v1 * wa; \
    b0 += v0 * wb; b1 += v1 * wb; }
    L2STEP(0, h0_0, h1_0)
    L2STEP(1, h0_1, h1_1)
    L2STEP(2, h0_2, h1_2)
    L2STEP(3, h0_3, h1_3)
    L2STEP(4, h0_4, h1_4)
    L2STEP(5, h0_5, h1_5)
    L2STEP(6, h0_6, h1_6)
    L2STEP(7, h0_7, h1_7)
#undef L2STEP
    float g0_0 = tanh_pre(a0.x), g1_0 = tanh_pre(a1.x);
    float g0_1 = tanh_pre(a0.y), g1_1 = tanh_pre(a1.y);
    float g0_2 = tanh_pre(a0.z), g1_2 = tanh_pre(a1.z);
    float g0_3 = tanh_pre(a0.w), g1_3 = tanh_pre(a1.w);
    float g0_4 = tanh_pre(b0.x), g1_4 = tanh_pre(b1.x);
    float g0_5 = tanh_pre(b0.y), g1_5 = tanh_pre(b1.y);
    float g0_6 = tanh_pre(b0.z), g1_6 = tanh_pre(b1.z);
    float g0_7 = tanh_pre(b0.w), g1_7 = tanh_pre(b1.w);

    // layer 3: shared weights (pre-scaled log2e), two chains x 4 accumulators
    f4 pa0 = *(const f4*)(wp + 200), pb0 = *(const f4*)(wp + 204);
    f4 pc0 = *(const f4*)(wp + 208), pd0 = *(const f4*)(wp + 212);
    f4 pa1 = pa0, pb1 = pb0, pc1 = pc0, pd1 = pd0;
#define L3STEP(GI, X0, X1) { \
    const float* wr = wp + 72 + (GI) * 16; \
    f4 w0 = *(const f4*)(wr); \
    f4 w1 = *(const f4*)(wr + 4); \
    f4 w2 = *(const f4*)(wr + 8); \
    f4 w3 = *(const f4*)(wr + 12); \
    f4 v0 = splat4(X0), v1 = splat4(X1); \
    pa0 += v0 * w0; pa1 += v1 * w0; \
    pb0 += v0 * w1; pb1 += v1 * w1; \
    pc0 += v0 * w2; pc1 += v1 * w2; \
    pd0 += v0 * w3; pd1 += v1 * w3; }
    L3STEP(0, g0_0, g1_0)
    L3STEP(1, g0_1, g1_1)
    L3STEP(2, g0_2, g1_2)
    L3STEP(3, g0_3, g1_3)
    L3STEP(4, g0_4, g1_4)
    L3STEP(5, g0_5, g1_5)
    L3STEP(6, g0_6, g1_6)
    L3STEP(7, g0_7, g1_7)
#undef L3STEP

    // p scalars, already in log2 domain (no arrays!)
    float p0_0 = pa0.x, p0_1 = pa0.y, p0_2 = pa0.z, p0_3 = pa0.w;
    float p0_4 = pb0.x, p0_5 = pb0.y, p0_6 = pb0.z, p0_7 = pb0.w;
    float p0_8 = pc0.x, p0_9 = pc0.y, p0_10 = pc0.z, p0_11 = pc0.w;
    float p0_12 = pd0.x, p0_13 = pd0.y;
    float p1_0 = pa1.x, p1_1 = pa1.y, p1_2 = pa1.z, p1_3 = pa1.w;
    float p1_4 = pb1.x, p1_5 = pb1.y, p1_6 = pb1.z, p1_7 = pb1.w;
    float p1_8 = pc1.x, p1_9 = pc1.y, p1_10 = pc1.z, p1_11 = pc1.w;
    float p1_12 = pd1.x, p1_13 = pd1.y;

    if (dd == 0) {   // wave-uniform override; convert to log2 domain
        p0_0 = LOG2E * ip[0];  p0_1 = LOG2E * ip[1];  p0_2 = LOG2E * ip[2];
        p0_3 = LOG2E * ip[3];  p0_4 = LOG2E * ip[4];  p0_5 = LOG2E * ip[5];
        p0_6 = LOG2E * ip[6];  p0_7 = LOG2E * ip[7];  p0_8 = LOG2E * ip[8];
        p0_9 = LOG2E * ip[9];  p0_10 = LOG2E * ip[10]; p0_11 = LOG2E * ip[11];
        p0_12 = LOG2E * ip[12]; p0_13 = LOG2E * ip[13];
        p1_0 = p0_0;  p1_1 = p0_1;  p1_2 = p0_2;  p1_3 = p0_3;
        p1_4 = p0_4;  p1_5 = p0_5;  p1_6 = p0_6;  p1_7 = p0_7;
        p1_8 = p0_8;  p1_9 = p0_9;  p1_10 = p0_10; p1_11 = p0_11;
        p1_12 = p0_12; p1_13 = p0_13;
    }

    // ---- packed spline: f4 lanes = (w_s0, h_s0, w_s1, h_s1); raw v_exp ----
    f4 e0, e1, e2, e3, e4;
    e0.x = exp2_fast(p0_0); e0.y = exp2_fast(p0_5); e0.z = exp2_fast(p1_0); e0.w = exp2_fast(p1_5);
    e1.x = exp2_fast(p0_1); e1.y = exp2_fast(p0_6); e1.z = exp2_fast(p1_1); e1.w = exp2_fast(p1_6);
    e2.x = exp2_fast(p0_2); e2.y = exp2_fast(p0_7); e2.z = exp2_fast(p1_2); e2.w = exp2_fast(p1_7);
    e3.x = exp2_fast(p0_3); e3.y = exp2_fast(p0_8); e3.z = exp2_fast(p1_3); e3.w = exp2_fast(p1_8);
    e4.x = exp2_fast(p0_4); e4.y = exp2_fast(p0_9); e4.z = exp2_fast(p1_4); e4.w = exp2_fast(p1_9);
    f4 es = (e0 + e1) + (e2 + e3) + e4;
    f4 nrm;
    nrm.x = 0.995f * rcp_fast(es.x); nrm.y = 0.995f * rcp_fast(es.y);
    nrm.z = 0.995f * rcp_fast(es.z); nrm.w = 0.995f * rcp_fast(es.w);

    const f4 minv = {MIN_Wc, MIN_Hc, MIN_Wc, MIN_Hc};
    f4 acc4 = splat4(0.f);
    acc4 += minv + nrm * e0;  f4 cb1 = splat4(2.f * Bc) * acc4 - splat4(Bc);
    acc4 += minv + nrm * e1;  f4 cb2 = splat4(2.f * Bc) * acc4 - splat4(Bc);
    acc4 += minv + nrm * e2;  f4 cb3 = splat4(2.f * Bc) * acc4 - splat4(Bc);
    acc4 += minv + nrm * e3;  f4 cb4 = splat4(2.f * Bc) * acc4 - splat4(Bc);

    const float xc0 = fminf(fmaxf(xf0, -Bc), Bc);
    const float xc1 = fminf(fmaxf(xf1, -Bc), Bc);

    // bin select: track LOWER and UPPER boundaries; widths via one sub at end
    float icw0 = -Bc, ich0 = -Bc, hw0 = cb1.x, hh0 = cb1.y;
    float icw1 = -Bc, ich1 = -Bc, hw1 = cb1.z, hh1 = cb1.w;
    float rv0 = p0_10, rvp0 = p0_10, rv1 = p1_10, rvp1 = p1_10;
    bool vone0 = true, vpone0 = false, vone1 = true, vpone1 = false;
    {
        bool c0 = xc0 >= cb1.x;               bool c1 = xc1 >= cb1.z;
        icw0 = c0 ? cb1.x : icw0;             icw1 = c1 ? cb1.z : icw1;
        ich0 = c0 ? cb1.y : ich0;             ich1 = c1 ? cb1.w : ich1;
        hw0  = c0 ? cb2.x : hw0;              hw1  = c1 ? cb2.z : hw1;
        hh0  = c0 ? cb2.y : hh0;              hh1  = c1 ? cb2.w : hh1;
        vone0 = c0 ? false : vone0;           vone1 = c1 ? false : vone1;
        rv0  = c0 ? p0_10 : rv0;              rv1  = c1 ? p1_10 : rv1;
        rvp0 = c0 ? p0_11 : rvp0;             rvp1 = c1 ? p1_11 : rvp1;
    }
    {
        bool c0 = xc0 >= cb2.x;               bool c1 = xc1 >= cb2.z;
        icw0 = c0 ? cb2.x : icw0;             icw1 = c1 ? cb2.z : icw1;
        ich0 = c0 ? cb2.y : ich0;             ich1 = c1 ? cb2.w : ich1;
        hw0  = c0 ? cb3.x : hw0;              hw1  = c1 ? cb3.z : hw1;
        hh0  = c0 ? cb3.y : hh0;              hh1  = c1 ? cb3.w : hh1;
        rv0  = c0 ? p0_11 : rv0;              rv1  = c1 ? p1_11 : rv1;
        rvp0 = c0 ? p0_12 : rvp0;             rvp1 = c1 ? p1_12 : rvp1;
    }
    {
        bool c0 = xc0 >= cb3.x;               bool c1 = xc1 >= cb3.z;
        icw0 = c0 ? cb3.x : icw0;             icw1 = c1 ? cb3.z : icw1;
        ich0 = c0 ? cb3.y : ich0;             ich1 = c1 ? cb3.w : ich1;
        hw0  = c0 ? cb4.x : hw0;              hw1  = c1 ? cb4.z : hw1;
        hh0  = c0 ? cb4.y : hh0;              hh1  = c1 ? cb4.w : hh1;
        rv0  = c0 ? p0_12 : rv0;              rv1  = c1 ? p1_12 : rv1;
        rvp0 = c0 ? p0_13 : rvp0;             rvp1 = c1 ? p1_13 : rvp1;
    }
    {
        bool c0 = xc0 >= cb4.x;               bool c1 = xc1 >= cb4.z;
        icw0 = c0 ? cb4.x : icw0;             icw1 = c1 ? cb4.z : icw1;
        ich0 = c0 ? cb4.y : ich0;             ich1 = c1 ? cb4.w : ich1;
        hw0  = c0 ? Bc : hw0;                 hw1  = c1 ? Bc : hw1;
        hh0  = c0 ? Bc : hh0;                 hh1  = c1 ? Bc : hh1;
        rv0  = c0 ? p0_13 : rv0;              rv1  = c1 ? p1_13 : rv1;
        vpone0 = c0;                          vpone1 = c1;
    }
    const float ibw0 = hw0 - icw0, ih0 = hh0 - ich0;
    const float ibw1 = hw1 - icw1, ih1 = hh1 - ich1;
    const float idv0   = vone0  ? 1.0f : MIN_Dc + softplus2(rv0);
    const float idv1   = vone1  ? 1.0f : MIN_Dc + softplus2(rv1);
    const float idvp0  = vpone0 ? 1.0f : MIN_Dc + softplus2(rvp0);
    const float idvp1_ = vpone1 ? 1.0f : MIN_Dc + softplus2(rvp1);

    const float ibr0 = rcp_fast(ibw0);        const float ibr1 = rcp_fast(ibw1);
    const float idl0 = ih0 * ibr0;            const float idl1 = ih1 * ibr1;
    const float th0 = (xc0 - icw0) * ibr0;    const float th1 = (xc1 - icw1) * ibr1;
    const float om0 = 1.0f - th0;             const float om1 = 1.0f - th1;
    const float tm0 = th0 * om0;              const float tm1 = th1 * om1;
    const float num0 = ih0 * (idl0 * th0 * th0 + idv0 * tm0);
    const float num1 = ih1 * (idl1 * th1 * th1 + idv1 * tm1);
    const float den0 = idl0 + (idv0 + idvp0 - 2.0f * idl0) * tm0;
    const float den1 = idl1 + (idv1 + idvp1_ - 2.0f * idl1) * tm1;
    const float dr0 = rcp_fast(den0);         const float dr1 = rcp_fast(den1);
    const float out0 = ich0 + num0 * dr0;     const float out1v = ich1 + num1 * dr1;
    const float dn0 = idl0 * idl0 * (idvp0 * th0 * th0 + 2.0f * idl0 * tm0 + idv0 * om0 * om0);
    const float dn1 = idl1 * idl1 * (idvp1_ * th1 * th1 + 2.0f * idl1 * tm1 + idv1 * om1 * om1);
    const float ld0 = LN2 * log2_fast(dn0 * dr0 * dr0);
    const float ld1 = LN2 * log2_fast(dn1 * dr1 * dr1);

    const bool in0 = (xf0 >= -Bc) && (xf0 <= Bc);
    const bool in1 = (xf1 >= -Bc) && (xf1 <= Bc);
    const float z0 = in0 ? out0 : xf0;        const float z1 = in1 ? out1v : xf1;
    float lv0 = in0 ? ld0 : 0.0f;             float lv1 = in1 ? ld1 : 0.0f;

    out[dd * NN + s0 + lane] = z0;            // coalesced
    out[dd * NN + s0 + 64 + lane] = z1;

    #pragma unroll
    for (int off = 32; off > 0; off >>= 1) {
        lv0 += __shfl_down(lv0, off);
        lv1 += __shfl_down(lv1, off);
    }
    if (lane == 0) {
        out[NN * DD + dd * (NN / 64) + 2 * bx]     = lv0;
        out[NN * DD + dd * (NN / 64) + 2 * bx + 1] = lv1;
    }
}

// ---------------- fused kernel -----------------------------------------------
// grid (256, 8): x = 128-sample tile, y = 8-dim group (y==7 slot7 -> dim 0).
// causality: y<4 -> l<32 -> only k<32 contributes (W1 pre-masked) -> 1 MFMA.
// (256,4): best measured config (R14); (256,6) regressed (R15).
__global__ __launch_bounds__(256, 4) void fused_kernel(
    const float* __restrict__ x, const float* __restrict__ init_param,
    const ushort* __restrict__ Bp, const float* __restrict__ b1,
    const float* __restrict__ W2, const float* __restrict__ b2,
    const float* __restrict__ W3, const float* __restrict__ b3,
    float* __restrict__ out)
{
    __shared__ ushort h1c[128 * H1S];    // 18432 B
    __shared__ float  wl[8 * WSL];       // 6912 B  -> total 25344 B
    const int tid = threadIdx.x;
    const int s0 = blockIdx.x * 128;
    const int y  = blockIdx.y;
    const int bx = blockIdx.x;
    const int lane = tid & 63;
    const int wave = __builtin_amdgcn_readfirstlane(tid >> 6);
    const int ln = lane & 15, qg = lane >> 4;
    const int l0 = y * 8;

    // spline x values for this wave's 2 dims x 2 sample-halves
    const int dA = y * 8 + 1 + 2 * wave;
    const int dB = (y == 7 && wave == 3) ? 0 : dA + 1;
    const float* xr0 = x + (size_t)(s0 + lane) * 64;
    const float* xr1 = xr0 + 64 * 64;
    float xA0 = xr0[dA], xA1 = xr1[dA];
    float xB0 = xr0[dB], xB1 = xr1[dB];

    // A-fragments for two m-tiles (rows wave*16 and 64+wave*16)
    short8 a0_0, a1_0, a0_1, a1_1;
    {
        const float* p0 = x + (size_t)(s0 + wave * 16 + ln) * 64 + qg * 8;
        const float* p1 = p0 + 64 * 64;
        a0_0 = pack_a(*(const f4*)p0, *(const f4*)(p0 + 4));
        a0_1 = pack_a(*(const f4*)p1, *(const f4*)(p1 + 4));
        if (y >= 4) {
            a1_0 = pack_a(*(const f4*)(p0 + 32), *(const f4*)(p0 + 36));
            a1_1 = pack_a(*(const f4*)(p1 + 32), *(const f4*)(p1 + 36));
        } else { a1_0 = a0_0; a1_1 = a0_1; }
    }

    // ---- stage this block's 8 dims of weights into LDS (log2-domain scaled) ----
    if (tid < 128) {   // W2: 8 slots x 64 floats, f4, x 2log2e
        int s = tid >> 4, o = (tid & 15) * 4;
        if (l0 + s < LL)
            *(f4*)&wl[s * WSL + o] = splat4(TWOLOG2E) * (*(const f4*)&W2[(l0 + s) * 64 + o]);
    }
    if (tid < 64) {    // b2: 8 x 8, x 2log2e
        int s = tid >> 3, o = tid & 7;
        if (l0 + s < LL) wl[s * WSL + 64 + o] = TWOLOG2E * b2[(l0 + s) * 8 + o];
    }
    #pragma unroll
    for (int q0 = 0; q0 < 448; q0 += 256) {   // W3: 8 slots x 56 f2, x log2e
        int q = q0 + tid;
        if (q < 448) {
            int s = q / 56, r = q % 56, g = r / 7, o = r % 7;
            if (l0 + s < LL)
                *(f2*)&wl[s * WSL + 72 + g * 16 + o * 2] =
                    splat2(LOG2E) * (*(const f2*)&W3[(l0 + s) * 112 + g * 14 + o * 2]);
        }
    }
    if (tid < 64) {    // zero W3 pad cols 14,15
        int s = tid >> 3, g = tid & 7;
        *(f2*)&wl[s * WSL + 72 + g * 16 + 14] = splat2(0.f);
    }
    if (tid < 112) {   // b3: 8 x 14, x log2e
        int s = tid / 14, o = tid % 14;
        wl[s * WSL + 200 + o] = LOG2E * b3[(l0 + s < LL ? l0 + s : 0) * PP + o];
    }
    if (tid < 16) {    // zero b3 pad
        int s = tid >> 1, o = 214 + (tid & 1);
        wl[s * WSL + o] = 0.f;
    }

    // ---- phase 1: MFMA 64 outcols x two 16-row m-tiles ----
    #pragma unroll
    for (int nt = 0; nt < 4; ++nt) {
        int ncol = y * 64 + nt * 16 + ln;
        const short8* bp8 = (const short8*)(Bp + ncol * 64 + qg * 8);
        short8 bf0 = bp8[0];
        f32x4 acc0 = {0.f, 0.f, 0.f, 0.f};
        f32x4 acc1 = {0.f, 0.f, 0.f, 0.f};
        acc0 = __builtin_amdgcn_mfma_f32_16x16x32_bf16(a0_0, bf0, acc0, 0, 0, 0);
        acc1 = __builtin_amdgcn_mfma_f32_16x16x32_bf16(a0_1, bf0, acc1, 0, 0, 0);
        if (y >= 4) {
            short8 bf1 = bp8[4];
            acc0 = __builtin_amdgcn_mfma_f32_16x16x32_bf16(a1_0, bf1, acc0, 0, 0, 0);
            acc1 = __builtin_amdgcn_mfma_f32_16x16x32_bf16(a1_1, bf1, acc1, 0, 0, 0);
        }
        float bias2 = (ncol < 504) ? TWOLOG2E * b1[ncol] : 0.f;
        #pragma unroll
        for (int r = 0; r < 4; ++r) {
            int row = wave * 16 + qg * 4 + r;
            float v0 = tanh_pre(fmaf(TWOLOG2E, acc0[r], bias2));
            float v1 = tanh_pre(fmaf(TWOLOG2E, acc1[r], bias2));
            h1c[row * H1S + nt * 16 + ln] = to_bf16t(v0);
            h1c[(row + 64) * H1S + nt * 16 + ln] = to_bf16t(v1);
        }
    }
    __syncthreads();   // the only barrier (covers weight staging + h1c)

    // h1 fragments: 2 dims x 2 sample-halves
    const int slA = 2 * wave, slB = 2 * wave + 1;
    uint4 hA0 = *(const uint4*)&h1c[lane * H1S + slA * 8];
    uint4 hA1 = *(const uint4*)&h1c[(lane + 64) * H1S + slA * 8];
    uint4 hB0 = *(const uint4*)&h1c[lane * H1S + slB * 8];
    uint4 hB1 = *(const uint4*)&h1c[(lane + 64) * H1S + slB * 8];

    // ---- phase 2: 2 dims, each with 2-sample ILP ----
    do_dim2(dA, wl + slA * WSL, xA0, xA1, hA0, hA1, s0, lane, bx, init_param, out);
    do_dim2(dB, wl + slB * WSL, xB0, xB1, hB0, hB1, s0, lane, bx, init_param, out);
}

extern "C" void kernel_launch(void* const* d_in, const int* in_sizes, int n_in,
                              void* d_out, int out_size, void* d_ws, size_t ws_size,
                              hipStream_t stream) {
    const float* x          = (const float*)d_in[0];
    const float* init_param = (const float*)d_in[1];
    const float* W1         = (const float*)d_in[2];
    const float* b1         = (const float*)d_in[3];
    const float* W2         = (const float*)d_in[4];
    const float* b2         = (const float*)d_in[5];
    const float* W3         = (const float*)d_in[6];
    const float* b3         = (const float*)d_in[7];
    float* out = (float*)d_out;

    ushort* Bp = (ushort*)d_ws;            // 512*64 bf16 = 64 KB

    pack_b1<<<128, 256, 0, stream>>>(W1, Bp);
    fused_kernel<<<dim3(256, 8), 256, 0, stream>>>(x, init_param, Bp, b1,
                                                   W2, b2, W3, b3, out);
}

// Round 17
// 104.225 us; speedup vs baseline: 1.0326x; 1.0074x over previous
//
#include <hip/hip_runtime.h>
#include <hip/hip_bf16.h>
#include <math.h>

#define KK 5
#define Bc 5.0f
#define NN 32768
#define DD 64
#define LL 63
#define PP 14
#define MIN_Wc 0.001f
#define MIN_Hc 0.001f
#define MIN_Dc 0.001f
#define LOG2E 1.44269504088896340736f
#define TWOLOG2E 2.88539008177792681472f
#define LN2 0.69314718055994530942f

typedef float f4 __attribute__((ext_vector_type(4)));
typedef float f32x4 __attribute__((ext_vector_type(4)));
typedef float f2 __attribute__((ext_vector_type(2)));
typedef short short8 __attribute__((ext_vector_type(8)));

__device__ __forceinline__ float rcp_fast(float v)   { return __builtin_amdgcn_rcpf(v); }
__device__ __forceinline__ float exp2_fast(float v)  { return __builtin_amdgcn_exp2f(v); }  // v_exp_f32: 2^x
__device__ __forceinline__ float log2_fast(float v)  { return __builtin_amdgcn_logf(v); }   // v_log_f32: log2
// input pre-scaled by 2*log2(e): tanh(x) = 1 - 2/(2^(2x*log2e)+1)
__device__ __forceinline__ float tanh_pre(float t2) {
    float e = exp2_fast(t2);
    return 1.0f - 2.0f * rcp_fast(e + 1.0f);
}
// input pre-scaled by log2(e): softplus(v) = ln2*log2(1+2^(v*log2e))
__device__ __forceinline__ float softplus2(float v2) {
    return (v2 > 21.7f) ? LN2 * v2 : LN2 * log2_fast(1.0f + exp2_fast(v2));
}
// truncating bf16 (1 shift); absmax margin ~3x covers the extra ulp
__device__ __forceinline__ ushort to_bf16t(float v) {
    return (ushort)(__float_as_uint(v) >> 16);
}
// pack two fp32 -> one u32 of two truncated bf16 (lo=v0, hi=v1)
__device__ __forceinline__ unsigned pack_bf16t2(float v0, float v1) {
    return (__float_as_uint(v0) >> 16) | (__float_as_uint(v1) & 0xFFFF0000u);
}
__device__ __forceinline__ float bflo(unsigned u) { return __uint_as_float(u << 16); }
__device__ __forceinline__ float bfhi(unsigned u) { return __uint_as_float(u & 0xFFFF0000u); }
__device__ __forceinline__ f2 splat2(float v) { f2 r; r.x = v; r.y = v; return r; }
__device__ __forceinline__ f4 splat4(float v) { f4 r; r.x = v; r.y = v; r.z = v; r.w = v; return r; }

__device__ __forceinline__ short8 pack_a(f4 v0, f4 v1) {
    short8 a;
    a[0] = (short)to_bf16t(v0.x); a[1] = (short)to_bf16t(v0.y);
    a[2] = (short)to_bf16t(v0.z); a[3] = (short)to_bf16t(v0.w);
    a[4] = (short)to_bf16t(v1.x); a[5] = (short)to_bf16t(v1.y);
    a[6] = (short)to_bf16t(v1.z); a[7] = (short)to_bf16t(v1.w);
    return a;
}

// per-dim LDS weight slot (floats, stride 216 = 864B, 16B-aligned):
// [0,64) 2log2e*W2[h][g]  [64,72) 2log2e*b2  [72,200) log2e*W3 padded [g][16]  [200,216) log2e*b3
#define WSL 216
#define H1S 72    // u16 row stride: 144B (proven residue, 0 measured conflicts)
#define BS  72    // Blds u16 row stride (same proven residue)

// ---- one dim, TWO samples per lane; NO local arrays (SROA-safe) ------------
__device__ __forceinline__ void do_dim2(
    int dd, const float* wp, float xf0, float xf1, uint4 hv0, uint4 hv1,
    int s0, int lane, int bx,
    const float* __restrict__ ip, float* __restrict__ out)
{
    // h1 unpack to scalars
    float h0_0 = bflo(hv0.x), h1_0 = bflo(hv1.x);
    float h0_1 = bfhi(hv0.x), h1_1 = bfhi(hv1.x);
    float h0_2 = bflo(hv0.y), h1_2 = bflo(hv1.y);
    float h0_3 = bfhi(hv0.y), h1_3 = bfhi(hv1.y);
    float h0_4 = bflo(hv0.z), h1_4 = bflo(hv1.z);
    float h0_5 = bfhi(hv0.z), h1_5 = bfhi(hv1.z);
    float h0_6 = bflo(hv0.w), h1_6 = bflo(hv1.w);
    float h0_7 = bfhi(hv0.w), h1_7 = bfhi(hv1.w);

    // layer 2: weights loaded once, two sample chains (weights pre-scaled 2log2e)
    f4 a0 = *(const f4*)(wp + 64), b0 = *(const f4*)(wp + 68);
    f4 a1 = a0, b1 = b0;
#define L2STEP(HI, X0, X1) { \
    f4 wa = *(const f4*)(wp + (HI) * 8); \
    f4 wb = *(const f4*)(wp + (HI) * 8 + 4); \
    f4 v0 = splat4(X0), v1 = splat4(X1); \
    a0 += v0 * wa; a1 += v1 * wa; \
    b0 += v0 * wb; b1 += v1 * wb; }
    L2STEP(0, h0_0, h1_0)
    L2STEP(1, h0_1, h1_1)
    L2STEP(2, h0_2, h1_2)
    L2STEP(3, h0_3, h1_3)
    L2STEP(4, h0_4, h1_4)
    L2STEP(5, h0_5, h1_5)
    L2STEP(6, h0_6, h1_6)
    L2STEP(7, h0_7, h1_7)
#undef L2STEP
    float g0_0 = tanh_pre(a0.x), g1_0 = tanh_pre(a1.x);
    float g0_1 = tanh_pre(a0.y), g1_1 = tanh_pre(a1.y);
    float g0_2 = tanh_pre(a0.z), g1_2 = tanh_pre(a1.z);
    float g0_3 = tanh_pre(a0.w), g1_3 = tanh_pre(a1.w);
    float g0_4 = tanh_pre(b0.x), g1_4 = tanh_pre(b1.x);
    float g0_5 = tanh_pre(b0.y), g1_5 = tanh_pre(b1.y);
    float g0_6 = tanh_pre(b0.z), g1_6 = tanh_pre(b1.z);
    float g0_7 = tanh_pre(b0.w), g1_7 = tanh_pre(b1.w);

    // layer 3: shared weights (pre-scaled log2e), two chains x 4 accumulators
    f4 pa0 = *(const f4*)(wp + 200), pb0 = *(const f4*)(wp + 204);
    f4 pc0 = *(const f4*)(wp + 208), pd0 = *(const f4*)(wp + 212);
    f4 pa1 = pa0, pb1 = pb0, pc1 = pc0, pd1 = pd0;
#define L3STEP(GI, X0, X1) { \
    const float* wr = wp + 72 + (GI) * 16; \
    f4 w0 = *(const f4*)(wr); \
    f4 w1 = *(const f4*)(wr + 4); \
    f4 w2 = *(const f4*)(wr + 8); \
    f4 w3 = *(const f4*)(wr + 12); \
    f4 v0 = splat4(X0), v1 = splat4(X1); \
    pa0 += v0 * w0; pa1 += v1 * w0; \
    pb0 += v0 * w1; pb1 += v1 * w1; \
    pc0 += v0 * w2; pc1 += v1 * w2; \
    pd0 += v0 * w3; pd1 += v1 * w3; }
    L3STEP(0, g0_0, g1_0)
    L3STEP(1, g0_1, g1_1)
    L3STEP(2, g0_2, g1_2)
    L3STEP(3, g0_3, g1_3)
    L3STEP(4, g0_4, g1_4)
    L3STEP(5, g0_5, g1_5)
    L3STEP(6, g0_6, g1_6)
    L3STEP(7, g0_7, g1_7)
#undef L3STEP

    // p scalars, already in log2 domain (no arrays!)
    float p0_0 = pa0.x, p0_1 = pa0.y, p0_2 = pa0.z, p0_3 = pa0.w;
    float p0_4 = pb0.x, p0_5 = pb0.y, p0_6 = pb0.z, p0_7 = pb0.w;
    float p0_8 = pc0.x, p0_9 = pc0.y, p0_10 = pc0.z, p0_11 = pc0.w;
    float p0_12 = pd0.x, p0_13 = pd0.y;
    float p1_0 = pa1.x, p1_1 = pa1.y, p1_2 = pa1.z, p1_3 = pa1.w;
    float p1_4 = pb1.x, p1_5 = pb1.y, p1_6 = pb1.z, p1_7 = pb1.w;
    float p1_8 = pc1.x, p1_9 = pc1.y, p1_10 = pc1.z, p1_11 = pc1.w;
    float p1_12 = pd1.x, p1_13 = pd1.y;

    if (dd == 0) {   // wave-uniform override; convert to log2 domain
        p0_0 = LOG2E * ip[0];  p0_1 = LOG2E * ip[1];  p0_2 = LOG2E * ip[2];
        p0_3 = LOG2E * ip[3];  p0_4 = LOG2E * ip[4];  p0_5 = LOG2E * ip[5];
        p0_6 = LOG2E * ip[6];  p0_7 = LOG2E * ip[7];  p0_8 = LOG2E * ip[8];
        p0_9 = LOG2E * ip[9];  p0_10 = LOG2E * ip[10]; p0_11 = LOG2E * ip[11];
        p0_12 = LOG2E * ip[12]; p0_13 = LOG2E * ip[13];
        p1_0 = p0_0;  p1_1 = p0_1;  p1_2 = p0_2;  p1_3 = p0_3;
        p1_4 = p0_4;  p1_5 = p0_5;  p1_6 = p0_6;  p1_7 = p0_7;
        p1_8 = p0_8;  p1_9 = p0_9;  p1_10 = p0_10; p1_11 = p0_11;
        p1_12 = p0_12; p1_13 = p0_13;
    }

    // ---- packed spline: f4 lanes = (w_s0, h_s0, w_s1, h_s1); raw v_exp ----
    f4 e0, e1, e2, e3, e4;
    e0.x = exp2_fast(p0_0); e0.y = exp2_fast(p0_5); e0.z = exp2_fast(p1_0); e0.w = exp2_fast(p1_5);
    e1.x = exp2_fast(p0_1); e1.y = exp2_fast(p0_6); e1.z = exp2_fast(p1_1); e1.w = exp2_fast(p1_6);
    e2.x = exp2_fast(p0_2); e2.y = exp2_fast(p0_7); e2.z = exp2_fast(p1_2); e2.w = exp2_fast(p1_7);
    e3.x = exp2_fast(p0_3); e3.y = exp2_fast(p0_8); e3.z = exp2_fast(p1_3); e3.w = exp2_fast(p1_8);
    e4.x = exp2_fast(p0_4); e4.y = exp2_fast(p0_9); e4.z = exp2_fast(p1_4); e4.w = exp2_fast(p1_9);
    f4 es = (e0 + e1) + (e2 + e3) + e4;
    f4 nrm;
    nrm.x = 0.995f * rcp_fast(es.x); nrm.y = 0.995f * rcp_fast(es.y);
    nrm.z = 0.995f * rcp_fast(es.z); nrm.w = 0.995f * rcp_fast(es.w);

    const f4 minv = {MIN_Wc, MIN_Hc, MIN_Wc, MIN_Hc};
    f4 acc4 = splat4(0.f);
    acc4 += minv + nrm * e0;  f4 cb1 = splat4(2.f * Bc) * acc4 - splat4(Bc);
    acc4 += minv + nrm * e1;  f4 cb2 = splat4(2.f * Bc) * acc4 - splat4(Bc);
    acc4 += minv + nrm * e2;  f4 cb3 = splat4(2.f * Bc) * acc4 - splat4(Bc);
    acc4 += minv + nrm * e3;  f4 cb4 = splat4(2.f * Bc) * acc4 - splat4(Bc);

    const float xc0 = fminf(fmaxf(xf0, -Bc), Bc);
    const float xc1 = fminf(fmaxf(xf1, -Bc), Bc);

    // bin select: track LOWER and UPPER boundaries; widths via one sub at end
    float icw0 = -Bc, ich0 = -Bc, hw0 = cb1.x, hh0 = cb1.y;
    float icw1 = -Bc, ich1 = -Bc, hw1 = cb1.z, hh1 = cb1.w;
    float rv0 = p0_10, rvp0 = p0_10, rv1 = p1_10, rvp1 = p1_10;
    bool vone0 = true, vpone0 = false, vone1 = true, vpone1 = false;
    {
        bool c0 = xc0 >= cb1.x;               bool c1 = xc1 >= cb1.z;
        icw0 = c0 ? cb1.x : icw0;             icw1 = c1 ? cb1.z : icw1;
        ich0 = c0 ? cb1.y : ich0;             ich1 = c1 ? cb1.w : ich1;
        hw0  = c0 ? cb2.x : hw0;              hw1  = c1 ? cb2.z : hw1;
        hh0  = c0 ? cb2.y : hh0;              hh1  = c1 ? cb2.w : hh1;
        vone0 = c0 ? false : vone0;           vone1 = c1 ? false : vone1;
        rv0  = c0 ? p0_10 : rv0;              rv1  = c1 ? p1_10 : rv1;
        rvp0 = c0 ? p0_11 : rvp0;             rvp1 = c1 ? p1_11 : rvp1;
    }
    {
        bool c0 = xc0 >= cb2.x;               bool c1 = xc1 >= cb2.z;
        icw0 = c0 ? cb2.x : icw0;             icw1 = c1 ? cb2.z : icw1;
        ich0 = c0 ? cb2.y : ich0;             ich1 = c1 ? cb2.w : ich1;
        hw0  = c0 ? cb3.x : hw0;              hw1  = c1 ? cb3.z : hw1;
        hh0  = c0 ? cb3.y : hh0;              hh1  = c1 ? cb3.w : hh1;
        rv0  = c0 ? p0_11 : rv0;              rv1  = c1 ? p1_11 : rv1;
        rvp0 = c0 ? p0_12 : rvp0;             rvp1 = c1 ? p1_12 : rvp1;
    }
    {
        bool c0 = xc0 >= cb3.x;               bool c1 = xc1 >= cb3.z;
        icw0 = c0 ? cb3.x : icw0;             icw1 = c1 ? cb3.z : icw1;
        ich0 = c0 ? cb3.y : ich0;             ich1 = c1 ? cb3.w : ich1;
        hw0  = c0 ? cb4.x : hw0;              hw1  = c1 ? cb4.z : hw1;
        hh0  = c0 ? cb4.y : hh0;              hh1  = c1 ? cb4.w : hh1;
        rv0  = c0 ? p0_12 : rv0;              rv1  = c1 ? p1_12 : rv1;
        rvp0 = c0 ? p0_13 : rvp0;             rvp1 = c1 ? p1_13 : rvp1;
    }
    {
        bool c0 = xc0 >= cb4.x;               bool c1 = xc1 >= cb4.z;
        icw0 = c0 ? cb4.x : icw0;             icw1 = c1 ? cb4.z : icw1;
        ich0 = c0 ? cb4.y : ich0;             ich1 = c1 ? cb4.w : ich1;
        hw0  = c0 ? Bc : hw0;                 hw1  = c1 ? Bc : hw1;
        hh0  = c0 ? Bc : hh0;                 hh1  = c1 ? Bc : hh1;
        rv0  = c0 ? p0_13 : rv0;              rv1  = c1 ? p1_13 : rv1;
        vpone0 = c0;                          vpone1 = c1;
    }
    const float ibw0 = hw0 - icw0, ih0 = hh0 - ich0;
    const float ibw1 = hw1 - icw1, ih1 = hh1 - ich1;
    const float idv0   = vone0  ? 1.0f : MIN_Dc + softplus2(rv0);
    const float idv1   = vone1  ? 1.0f : MIN_Dc + softplus2(rv1);
    const float idvp0  = vpone0 ? 1.0f : MIN_Dc + softplus2(rvp0);
    const float idvp1_ = vpone1 ? 1.0f : MIN_Dc + softplus2(rvp1);

    const float ibr0 = rcp_fast(ibw0);        const float ibr1 = rcp_fast(ibw1);
    const float idl0 = ih0 * ibr0;            const float idl1 = ih1 * ibr1;
    const float th0 = (xc0 - icw0) * ibr0;    const float th1 = (xc1 - icw1) * ibr1;
    const float om0 = 1.0f - th0;             const float om1 = 1.0f - th1;
    const float tm0 = th0 * om0;              const float tm1 = th1 * om1;
    const float num0 = ih0 * (idl0 * th0 * th0 + idv0 * tm0);
    const float num1 = ih1 * (idl1 * th1 * th1 + idv1 * tm1);
    const float den0 = idl0 + (idv0 + idvp0 - 2.0f * idl0) * tm0;
    const float den1 = idl1 + (idv1 + idvp1_ - 2.0f * idl1) * tm1;
    const float dr0 = rcp_fast(den0);         const float dr1 = rcp_fast(den1);
    const float out0 = ich0 + num0 * dr0;     const float out1v = ich1 + num1 * dr1;
    const float dn0 = idl0 * idl0 * (idvp0 * th0 * th0 + 2.0f * idl0 * tm0 + idv0 * om0 * om0);
    const float dn1 = idl1 * idl1 * (idvp1_ * th1 * th1 + 2.0f * idl1 * tm1 + idv1 * om1 * om1);
    const float ld0 = LN2 * log2_fast(dn0 * dr0 * dr0);
    const float ld1 = LN2 * log2_fast(dn1 * dr1 * dr1);

    const bool in0 = (xf0 >= -Bc) && (xf0 <= Bc);
    const bool in1 = (xf1 >= -Bc) && (xf1 <= Bc);
    const float z0 = in0 ? out0 : xf0;        const float z1 = in1 ? out1v : xf1;
    float lv0 = in0 ? ld0 : 0.0f;             float lv1 = in1 ? ld1 : 0.0f;

    out[dd * NN + s0 + lane] = z0;            // coalesced
    out[dd * NN + s0 + 64 + lane] = z1;

    #pragma unroll
    for (int off = 32; off > 0; off >>= 1) {
        lv0 += __shfl_down(lv0, off);
        lv1 += __shfl_down(lv1, off);
    }
    if (lane == 0) {
        out[NN * DD + dd * (NN / 64) + 2 * bx]     = lv0;
        out[NN * DD + dd * (NN / 64) + 2 * bx + 1] = lv1;
    }
}

// ---------------- fully fused single kernel ----------------------------------
// grid (256, 8): x = 128-sample tile, y = 8-dim group (y==7 slot7 -> dim 0).
// causality: y<4 -> l<32 -> only k<32 contributes (W1 pre-masked) -> 1 MFMA.
// W1 B-tile now staged per-block into LDS (removes the pack_b1 launch).
__global__ __launch_bounds__(256, 4) void fused_kernel(
    const float* __restrict__ x, const float* __restrict__ init_param,
    const float* __restrict__ W1, const float* __restrict__ b1,
    const float* __restrict__ W2, const float* __restrict__ b2,
    const float* __restrict__ W3, const float* __restrict__ b3,
    float* __restrict__ out)
{
    __shared__ ushort h1c[128 * H1S];    // 18432 B
    __shared__ float  wl[8 * WSL];       // 6912 B
    __shared__ ushort Blds[64 * BS];     // 9216 B  -> total 34560 B, 4 blocks/CU
    const int tid = threadIdx.x;
    const int s0 = blockIdx.x * 128;
    const int y  = blockIdx.y;
    const int bx = blockIdx.x;
    const int lane = tid & 63;
    const int wave = __builtin_amdgcn_readfirstlane(tid >> 6);
    const int ln = lane & 15, qg = lane >> 4;
    const int l0 = y * 8;

    // spline x values for this wave's 2 dims x 2 sample-halves
    const int dA = y * 8 + 1 + 2 * wave;
    const int dB = (y == 7 && wave == 3) ? 0 : dA + 1;
    const float* xr0 = x + (size_t)(s0 + lane) * 64;
    const float* xr1 = xr0 + 64 * 64;
    float xA0 = xr0[dA], xA1 = xr1[dA];
    float xB0 = xr0[dB], xB1 = xr1[dB];

    // A-fragments for two m-tiles (rows wave*16 and 64+wave*16)
    short8 a0_0, a1_0, a0_1, a1_1;
    {
        const float* p0 = x + (size_t)(s0 + wave * 16 + ln) * 64 + qg * 8;
        const float* p1 = p0 + 64 * 64;
        a0_0 = pack_a(*(const f4*)p0, *(const f4*)(p0 + 4));
        a0_1 = pack_a(*(const f4*)p1, *(const f4*)(p1 + 4));
        if (y >= 4) {
            a1_0 = pack_a(*(const f4*)(p0 + 32), *(const f4*)(p0 + 36));
            a1_1 = pack_a(*(const f4*)(p1 + 32), *(const f4*)(p1 + 36));
        } else { a1_0 = a0_0; a1_1 = a0_1; }
    }

    // ---- stage B-tile from W1: Blds[n_local][k] bf16, n = y*64+n_local ----
    // B[n][k] = W1[(l*63+k)*8+h], l=n>>3, h=n&7; 0 if n>=504 or k>=63.
    // y<4: only k<32 is ever read (causal) -> stage half.
    {
        const int n_local = tid >> 2;
        const int n = y * 64 + n_local;
        const int l = n >> 3, h = n & 7;
        const float* src = W1 + (size_t)l * 63 * 8 + h;   // + k*8 per k
        unsigned* drow = (unsigned*)&Blds[n_local * BS];
        if (y < 4) {
            const int kc0 = (tid & 3) * 8;
            #pragma unroll
            for (int j = 0; j < 4; ++j) {
                int k = kc0 + 2 * j;                      // k<32<63, n<256<504: no guards
                float v0 = src[(size_t)k * 8];
                float v1 = src[(size_t)(k + 1) * 8];
                drow[(kc0 >> 1) + j] = pack_bf16t2(v0, v1);
            }
        } else {
            const int kc0 = (tid & 3) * 16;
            #pragma unroll
            for (int j = 0; j < 8; ++j) {
                int k = kc0 + 2 * j;
                float v0 = (n < 504 && k < 63)     ? src[(size_t)k * 8]       : 0.f;
                float v1 = (n < 504 && k + 1 < 63) ? src[(size_t)(k + 1) * 8] : 0.f;
                drow[(kc0 >> 1) + j] = pack_bf16t2(v0, v1);
            }
        }
    }

    // ---- stage this block's 8 dims of weights into LDS (log2-domain scaled) ----
    if (tid < 128) {   // W2: 8 slots x 64 floats, f4, x 2log2e
        int s = tid >> 4, o = (tid & 15) * 4;
        if (l0 + s < LL)
            *(f4*)&wl[s * WSL + o] = splat4(TWOLOG2E) * (*(const f4*)&W2[(l0 + s) * 64 + o]);
    }
    if (tid < 64) {    // b2: 8 x 8, x 2log2e
        int s = tid >> 3, o = tid & 7;
        if (l0 + s < LL) wl[s * WSL + 64 + o] = TWOLOG2E * b2[(l0 + s) * 8 + o];
    }
    #pragma unroll
    for (int q0 = 0; q0 < 448; q0 += 256) {   // W3: 8 slots x 56 f2, x log2e
        int q = q0 + tid;
        if (q < 448) {
            int s = q / 56, r = q % 56, g = r / 7, o = r % 7;
            if (l0 + s < LL)
                *(f2*)&wl[s * WSL + 72 + g * 16 + o * 2] =
                    splat2(LOG2E) * (*(const f2*)&W3[(l0 + s) * 112 + g * 14 + o * 2]);
        }
    }
    if (tid < 64) {    // zero W3 pad cols 14,15
        int s = tid >> 3, g = tid & 7;
        *(f2*)&wl[s * WSL + 72 + g * 16 + 14] = splat2(0.f);
    }
    if (tid < 112) {   // b3: 8 x 14, x log2e
        int s = tid / 14, o = tid % 14;
        wl[s * WSL + 200 + o] = LOG2E * b3[(l0 + s < LL ? l0 + s : 0) * PP + o];
    }
    if (tid < 16) {    // zero b3 pad
        int s = tid >> 1, o = 214 + (tid & 1);
        wl[s * WSL + o] = 0.f;
    }
    __syncthreads();   // Blds + wl ready

    // ---- phase 1: MFMA 64 outcols x two 16-row m-tiles (B from LDS) ----
    #pragma unroll
    for (int nt = 0; nt < 4; ++nt) {
        int ncol = y * 64 + nt * 16 + ln;
        const ushort* brow = &Blds[(nt * 16 + ln) * BS + qg * 8];
        short8 bf0 = *(const short8*)brow;
        f32x4 acc0 = {0.f, 0.f, 0.f, 0.f};
        f32x4 acc1 = {0.f, 0.f, 0.f, 0.f};
        acc0 = __builtin_amdgcn_mfma_f32_16x16x32_bf16(a0_0, bf0, acc0, 0, 0, 0);
        acc1 = __builtin_amdgcn_mfma_f32_16x16x32_bf16(a0_1, bf0, acc1, 0, 0, 0);
        if (y >= 4) {
            short8 bf1 = *(const short8*)(brow + 32);
            acc0 = __builtin_amdgcn_mfma_f32_16x16x32_bf16(a1_0, bf1, acc0, 0, 0, 0);
            acc1 = __builtin_amdgcn_mfma_f32_16x16x32_bf16(a1_1, bf1, acc1, 0, 0, 0);
        }
        float bias2 = (ncol < 504) ? TWOLOG2E * b1[ncol] : 0.f;
        #pragma unroll
        for (int r = 0; r < 4; ++r) {
            int row = wave * 16 + qg * 4 + r;
            float v0 = tanh_pre(fmaf(TWOLOG2E, acc0[r], bias2));
            float v1 = tanh_pre(fmaf(TWOLOG2E, acc1[r], bias2));
            h1c[row * H1S + nt * 16 + ln] = to_bf16t(v0);
            h1c[(row + 64) * H1S + nt * 16 + ln] = to_bf16t(v1);
        }
    }
    __syncthreads();   // h1c ready

    // h1 fragments: 2 dims x 2 sample-halves
    const int slA = 2 * wave, slB = 2 * wave + 1;
    uint4 hA0 = *(const uint4*)&h1c[lane * H1S + slA * 8];
    uint4 hA1 = *(const uint4*)&h1c[(lane + 64) * H1S + slA * 8];
    uint4 hB0 = *(const uint4*)&h1c[lane * H1S + slB * 8];
    uint4 hB1 = *(const uint4*)&h1c[(lane + 64) * H1S + slB * 8];

    // ---- phase 2: 2 dims, each with 2-sample ILP ----
    do_dim2(dA, wl + slA * WSL, xA0, xA1, hA0, hA1, s0, lane, bx, init_param, out);
    do_dim2(dB, wl + slB * WSL, xB0, xB1, hB0, hB1, s0, lane, bx, init_param, out);
}

extern "C" void kernel_launch(void* const* d_in, const int* in_sizes, int n_in,
                              void* d_out, int out_size, void* d_ws, size_t ws_size,
                              hipStream_t stream) {
    const float* x          = (const float*)d_in[0];
    const float* init_param = (const float*)d_in[1];
    const float* W1         = (const float*)d_in[2];
    const float* b1         = (const float*)d_in[3];
    const float* W2         = (const float*)d_in[4];
    const float* b2         = (const float*)d_in[5];
    const float* W3         = (const float*)d_in[6];
    const float* b3         = (const float*)d_in[7];
    float* out = (float*)d_out;

    // single launch; d_ws unused
    fused_kernel<<<dim3(256, 8), 256, 0, stream>>>(x, init_param, W1, b1,
                                                   W2, b2, W3, b3, out);
}